// Round 20
// baseline (530.146 us; speedup 1.0000x reference)
//
#include <hip/hip_runtime.h>
#include <hip/hip_bf16.h>
#include <float.h>
#include <math.h>

#define ROWS 8192     // B*S
#define NF   10000    // n_fillers
#define NPAD 10240    // 80 * 128

typedef short s8v __attribute__((ext_vector_type(8)));
typedef float f4v __attribute__((ext_vector_type(4)));

#define GLD16(g, l) __builtin_amdgcn_global_load_lds((const __attribute__((address_space(1))) void*)(g), (__attribute__((address_space(3))) void*)(l), 16, 0, 0)

__device__ inline unsigned short f2bf(float x) {
  __hip_bfloat16 h = __float2bfloat16(x);
  return __builtin_bit_cast(unsigned short, h);
}
__device__ inline float bf2f(unsigned short u) {
  __hip_bfloat16 h = __builtin_bit_cast(__hip_bfloat16, u);
  return __bfloat162float(h);
}

// ---------------- filler: row norms + hi/lo bf16 conversion (rows padded to NPAD) ----------------
__global__ __launch_bounds__(256) void k_cvt_filler(const float* __restrict__ filler,
                                                    unsigned short* __restrict__ fl2,
                                                    float* __restrict__ fln) {
  int row = blockIdx.x * 4 + (threadIdx.x >> 6);
  int lane = threadIdx.x & 63;
  if (row >= NPAD) return;
  if (row < NF) {
    float4 v = reinterpret_cast<const float4*>(filler + (size_t)row * 256)[lane];
    float s = v.x * v.x + v.y * v.y + v.z * v.z + v.w * v.w;
    #pragma unroll
    for (int off = 32; off >= 1; off >>= 1) s += __shfl_xor(s, off, 64);
    if (lane == 0) fln[row] = s;
    float xs[4] = {v.x, v.y, v.z, v.w};
    unsigned short h[4], lo[4];
    #pragma unroll
    for (int j = 0; j < 4; ++j) { h[j] = f2bf(xs[j]); lo[j] = f2bf(xs[j] - bf2f(h[j])); }
    uint2 hh = make_uint2(h[0] | ((unsigned)h[1] << 16), h[2] | ((unsigned)h[3] << 16));
    uint2 ll = make_uint2(lo[0] | ((unsigned)lo[1] << 16), lo[2] | ((unsigned)lo[3] << 16));
    *reinterpret_cast<uint2*>(fl2 + (size_t)row * 512 + lane * 4) = hh;
    *reinterpret_cast<uint2*>(fl2 + (size_t)row * 512 + 256 + lane * 4) = ll;
  } else {
    *reinterpret_cast<uint2*>(fl2 + (size_t)row * 512 + lane * 4) = make_uint2(0, 0);
    *reinterpret_cast<uint2*>(fl2 + (size_t)row * 512 + 256 + lane * 4) = make_uint2(0, 0);
    if (lane == 0) fln[row] = 1e30f;
  }
}

// ---------------- GEMM1: ht[b, r*256+f] = sum_k hidden[b,k]*W[f*256+r,k] + bias[f*256+r]
__global__ __launch_bounds__(256) void k_gemm1(const float* __restrict__ hidden,
                                               const float* __restrict__ W,
                                               const float* __restrict__ bias,
                                               float* __restrict__ ht) {
  __shared__ float As[64][68];
  __shared__ float Bs[64][136];
  __shared__ float biasS[128];
  const int tid = threadIdx.x;
  const int nbase = blockIdx.x * 128;
  const int r = nbase >> 8;
  const int f0 = nbase & 255;
  const int tm = tid >> 4, tn = tid & 15;
  const int m0 = tm * 4, n0 = tn * 8;

  if (tid < 128) biasS[tid] = bias[(size_t)(f0 + tid) * 256 + r];

  float acc[4][8];
  #pragma unroll
  for (int i = 0; i < 4; ++i)
    #pragma unroll
    for (int j = 0; j < 8; ++j) acc[i][j] = 0.f;

  for (int kt = 0; kt < 16; ++kt) {
    __syncthreads();
    #pragma unroll
    for (int i = 0; i < 4; ++i) {
      int q = tid + i * 256;
      int b = q >> 4, kq = q & 15;
      float4 v = *reinterpret_cast<const float4*>(hidden + (size_t)b * 1024 + kt * 64 + kq * 4);
      As[kq * 4 + 0][b] = v.x;
      As[kq * 4 + 1][b] = v.y;
      As[kq * 4 + 2][b] = v.z;
      As[kq * 4 + 3][b] = v.w;
    }
    #pragma unroll
    for (int i = 0; i < 8; ++i) {
      int q = tid + i * 256;
      int nl = q >> 4, kq = q & 15;
      size_t wrow = (size_t)(f0 + nl) * 256 + r;
      float4 v = *reinterpret_cast<const float4*>(W + wrow * 1024 + kt * 64 + kq * 4);
      Bs[kq * 4 + 0][nl] = v.x;
      Bs[kq * 4 + 1][nl] = v.y;
      Bs[kq * 4 + 2][nl] = v.z;
      Bs[kq * 4 + 3][nl] = v.w;
    }
    __syncthreads();
    #pragma unroll
    for (int kk = 0; kk < 64; ++kk) {
      float4 a  = *reinterpret_cast<const float4*>(&As[kk][m0]);
      float4 b0 = *reinterpret_cast<const float4*>(&Bs[kk][n0]);
      float4 b1 = *reinterpret_cast<const float4*>(&Bs[kk][n0 + 4]);
      float av[4] = {a.x, a.y, a.z, a.w};
      float bv[8] = {b0.x, b0.y, b0.z, b0.w, b1.x, b1.y, b1.z, b1.w};
      #pragma unroll
      for (int i = 0; i < 4; ++i)
        #pragma unroll
        for (int j = 0; j < 8; ++j) acc[i][j] += av[i] * bv[j];
    }
  }
  #pragma unroll
  for (int i = 0; i < 4; ++i) {
    int b = m0 + i;
    float4 o0 = make_float4(acc[i][0] + biasS[n0 + 0], acc[i][1] + biasS[n0 + 1],
                            acc[i][2] + biasS[n0 + 2], acc[i][3] + biasS[n0 + 3]);
    float4 o1 = make_float4(acc[i][4] + biasS[n0 + 4], acc[i][5] + biasS[n0 + 5],
                            acc[i][6] + biasS[n0 + 6], acc[i][7] + biasS[n0 + 7]);
    float* p = ht + (size_t)b * 65536 + nbase + n0;
    *reinterpret_cast<float4*>(p)     = o0;
    *reinterpret_cast<float4*>(p + 4) = o1;
  }
}

// ---------------- fg (fused): compute fg, emit hi/lo bf16 (K-concat) + row norms ----------------
__global__ __launch_bounds__(256) void k_fg2(const int* __restrict__ roles,
                                             const float* __restrict__ role_emb,
                                             const float* __restrict__ ht,
                                             unsigned short* __restrict__ fg2,
                                             float* __restrict__ fgn) {
  __shared__ float As[64][40];
  __shared__ float Bs[64][264];
  __shared__ int sidx[32];
  const int tid = threadIdx.x;
  const int b = blockIdx.x >> 2;
  const int sbase = (blockIdx.x & 3) * 32;
  const int tm = tid >> 5, tn = tid & 31;
  const int m0 = tm * 4, n0 = tn * 8;
  if (tid < 32) sidx[tid] = roles[b * 128 + sbase + tid];

  float acc[4][8];
  #pragma unroll
  for (int i = 0; i < 4; ++i)
    #pragma unroll
    for (int j = 0; j < 8; ++j) acc[i][j] = 0.f;

  for (int kt = 0; kt < 4; ++kt) {
    __syncthreads();
    #pragma unroll
    for (int i = 0; i < 2; ++i) {
      int q = tid + i * 256;
      int s = q >> 4, rq = q & 15;
      float4 v = *reinterpret_cast<const float4*>(role_emb + (size_t)sidx[s] * 256 + kt * 64 + rq * 4);
      As[rq * 4 + 0][s] = v.x;
      As[rq * 4 + 1][s] = v.y;
      As[rq * 4 + 2][s] = v.z;
      As[rq * 4 + 3][s] = v.w;
    }
    #pragma unroll
    for (int i = 0; i < 16; ++i) {
      int q = tid + i * 256;
      int rr = q >> 6, fq = q & 63;
      float4 v = *reinterpret_cast<const float4*>(ht + (size_t)b * 65536 + (size_t)(kt * 64 + rr) * 256 + fq * 4);
      *reinterpret_cast<float4*>(&Bs[rr][fq * 4]) = v;
    }
    __syncthreads();
    #pragma unroll
    for (int kk = 0; kk < 64; ++kk) {
      float4 a  = *reinterpret_cast<const float4*>(&As[kk][m0]);
      float4 b0 = *reinterpret_cast<const float4*>(&Bs[kk][n0]);
      float4 b1 = *reinterpret_cast<const float4*>(&Bs[kk][n0 + 4]);
      float av[4] = {a.x, a.y, a.z, a.w};
      float bv[8] = {b0.x, b0.y, b0.z, b0.w, b1.x, b1.y, b1.z, b1.w};
      #pragma unroll
      for (int i = 0; i < 4; ++i)
        #pragma unroll
        for (int j = 0; j < 8; ++j) acc[i][j] += av[i] * bv[j];
    }
  }
  #pragma unroll
  for (int i = 0; i < 4; ++i) {
    const int grow = b * 128 + sbase + m0 + i;
    float nrm = 0.f;
    unsigned int hp[4], lp[4];
    #pragma unroll
    for (int j = 0; j < 8; j += 2) {
      float x0 = acc[i][j], x1 = acc[i][j + 1];
      nrm += x0 * x0 + x1 * x1;
      unsigned short h0 = f2bf(x0), h1 = f2bf(x1);
      unsigned short l0 = f2bf(x0 - bf2f(h0)), l1 = f2bf(x1 - bf2f(h1));
      hp[j >> 1] = h0 | ((unsigned)h1 << 16);
      lp[j >> 1] = l0 | ((unsigned)l1 << 16);
    }
    *reinterpret_cast<uint4*>(fg2 + (size_t)grow * 512 + n0)       = make_uint4(hp[0], hp[1], hp[2], hp[3]);
    *reinterpret_cast<uint4*>(fg2 + (size_t)grow * 512 + 256 + n0) = make_uint4(lp[0], lp[1], lp[2], lp[3]);
    #pragma unroll
    for (int msk = 1; msk <= 16; msk <<= 1) nrm += __shfl_xor(nrm, msk, 64);
    if (tn == 0) fgn[grow] = nrm;
  }
}

// ---------------- MFMA distance GEMM: 128x128 tile, 4 waves of 64x64, BK=32, 3 blocks/CU -------
// LDS reads 0.5 b128/MFMA (vs 0.75 at 64x32 tiles): total 3.9GB vs 6.0GB. dbuf 2x16KB + 17KB scr
// = 50KB -> 3 blocks/CU (12 waves). R6-proven 64B-row swizzle slot = oct ^ ((row>>1)&3).
// Same grid/mapping/staging mechanics/nt-store epilogue as R15. Stats in k_final (R19).
__global__ __launch_bounds__(256, 3) void k_dist(const unsigned short* __restrict__ fg2,
                                                 const unsigned short* __restrict__ fl2,
                                                 const float* __restrict__ fgn,
                                                 const float* __restrict__ fln,
                                                 float* __restrict__ out) {
  __shared__ __align__(16) char lds[2][16384];    // per buf: A 8KB | B 8KB (128 rows x 32 k each)
  __shared__ __align__(16) float scr[4224];       // 32 rows x 132 f32 bounce
  __shared__ float rn2s[128];
  const int tid = threadIdx.x;
  const int w = tid >> 6, l = tid & 63;
  const int g = l >> 4, lr = l & 15;
  const int mt  = (blockIdx.x & 7) * 8 + ((blockIdx.x >> 3) & 7);   // XCD gets 8 A-panels
  const int grp = blockIdx.x >> 6;                                  // 0..7
  const int rbase = mt << 7;
  const int wm = (w >> 1) << 6;   // 0 / 64
  const int wn = (w & 1) << 6;    // 0 / 64

  if (tid < 128) rn2s[tid] = fgn[rbase + tid];

  // staging: 512 chunks (16B = 8 elems) per 128x32 matrix tile; 2 A + 2 B chunks per thread.
  // pre-swizzled global source: oct' = oct ^ ((row>>1)&3)  [R6-proven for 64B rows]
  int rowC[2], swC[2];
  #pragma unroll
  for (int t = 0; t < 2; ++t) {
    int p = tid + t * 256;
    int row = p >> 2, oct = p & 3;
    rowC[t] = row;
    swC[t] = (oct ^ ((row >> 1) & 3)) << 3;
  }
  // ds_read offsets: row stride 64B, matching XOR
  int offA[4], offB[4];
  #pragma unroll
  for (int i = 0; i < 4; ++i) { int r = wm + i * 16 + lr; offA[i] = r * 64 + ((g ^ ((r >> 1) & 3)) << 4); }
  #pragma unroll
  for (int j = 0; j < 4; ++j) { int r = wn + j * 16 + lr; offB[j] = 8192 + r * 64 + ((g ^ ((r >> 1) & 3)) << 4); }

  // hi/lo K mapping over [hi(256)|lo(256)] rows: kt 0-7 hiA*hiB, 8-15 loA*hiB, 16-23 hiA*loB
  auto kAof = [](int kt) { return ((kt & 7) << 5) + ((kt >= 8 && kt < 16) ? 256 : 0); };
  auto kBof = [](int kt) { return ((kt & 7) << 5) + ((kt >= 16) ? 256 : 0); };

  auto stage = [&](int buf, int kt, int nb) {
    const int kA = kAof(kt), kB = kBof(kt);
    char* bA = &lds[buf][0]    + w * 1024;
    char* bB = &lds[buf][8192] + w * 1024;
    #pragma unroll
    for (int t = 0; t < 2; ++t) {
      GLD16(fg2 + ((size_t)(rbase + rowC[t]) * 512 + kA + swC[t]), bA + t * 4096);
      GLD16(fl2 + ((size_t)(nb    + rowC[t]) * 512 + kB + swC[t]), bB + t * 4096);
    }
  };

  stage(0, 0, grp << 7);   // prologue for strip 0
  __syncthreads();

  for (int s = 0; s < 10; ++s) {
    const int nt = grp + s * 8;
    const int nbase = nt << 7;
    float cnr[4];
    #pragma unroll
    for (int j = 0; j < 4; ++j) cnr[j] = fln[nbase + wn + (j << 4) + lr];

    f4v acc[4][4];
    #pragma unroll
    for (int i = 0; i < 4; ++i)
      #pragma unroll
      for (int j = 0; j < 4; ++j) acc[i][j] = (f4v)0.f;

    for (int kt = 0; kt < 24; ++kt) {
      if (kt < 23)      stage((kt + 1) & 1, kt + 1, nbase);
      else if (s < 9)   stage(0, 0, (nt + 8) << 7);   // cross-strip prefetch into buf0
      const char* A = lds[kt & 1];
      s8v va[4], vb[4];
      #pragma unroll
      for (int i = 0; i < 4; ++i) va[i] = *reinterpret_cast<const s8v*>(A + offA[i]);
      #pragma unroll
      for (int j = 0; j < 4; ++j) vb[j] = *reinterpret_cast<const s8v*>(A + offB[j]);
      #pragma unroll
      for (int i = 0; i < 4; ++i)
        #pragma unroll
        for (int j = 0; j < 4; ++j)
          acc[i][j] = __builtin_amdgcn_mfma_f32_16x16x32_bf16(va[i], vb[j], acc[i][j], 0, 0, 0);
      __syncthreads();
    }

    // ---- lean epilogue: d=sqrt(...), bounce via scr (separate region), nt f4 stores ----
    const int rem = NF - nbase;
    const int c4lim = (rem >= 128) ? 32 : (rem > 0 ? (rem >> 2) : 0);
    const int lbase = (wm >> 6) << 4;                    // 0 or 16

    #pragma unroll
    for (int i = 0; i < 4; ++i) {
      #pragma unroll
      for (int j = 0; j < 4; ++j) {
        const int cloc = wn + (j << 4) + lr;
        #pragma unroll
        for (int r = 0; r < 4; ++r) {
          const int lrow = lbase + (g << 2) + r;
          const float r2 = rn2s[wm + (i << 4) + (g << 2) + r];
          float d = sqrtf(fmaxf(r2 - 2.0f * acc[i][j][r] + cnr[j], 0.f));
          scr[lrow * 132 + cloc] = d;
        }
      }
      __syncthreads();
      #pragma unroll
      for (int t2 = 0; t2 < 4; ++t2) {
        const int id2 = tid + (t2 << 8);
        const int rr2 = id2 >> 5, c4 = id2 & 31;
        f4v v = *reinterpret_cast<const f4v*>(scr + rr2 * 132 + (c4 << 2));
        if (c4 < c4lim) {
          const int grow = rbase + ((rr2 < 16) ? ((i << 4) + rr2) : (64 + (i << 4) + rr2 - 16));
          __builtin_nontemporal_store(v, reinterpret_cast<f4v*>(out + (size_t)grow * NF + nbase + (c4 << 2)));
        }
      }
      __syncthreads();
    }
  }
}

// ---------------- per-row: LDS-staged, ONLINE softmax in pass 1, then logp = -d - LSE ----------
__global__ __launch_bounds__(256) void k_final(float* __restrict__ out) {
  const int row = blockIdx.x;
  __shared__ __align__(16) float rowd[10000];
  __shared__ float red[16];
  const int t = threadIdx.x;
  const int w = t >> 6, l = t & 63;
  float* po = out + (size_t)row * NF;

  // pass 1: nt-load -> LDS stage + per-thread ONLINE (min, argmin, sum exp(m - d))
  float bd = FLT_MAX; int bi = 0; float s = 0.f;
  for (int c = t; c < 2500; c += 256) {
    f4v v = __builtin_nontemporal_load(reinterpret_cast<const f4v*>(po) + c);
    *reinterpret_cast<f4v*>(&rowd[c * 4]) = v;
    const int base = c * 4;
    #pragma unroll
    for (int q = 0; q < 4; ++q) {
      float d = v[q];
      if (d < bd) {            // new min: rescale, then this elem contributes exp(0)=1
        s = s * __expf(d - bd) + 1.f;
        bd = d; bi = base + q;
      } else {
        s += __expf(bd - d);
      }
    }
  }
  // wave reduce: LSE-merge (m,s) + argmin with index tie-break
  #pragma unroll
  for (int msk = 1; msk <= 32; msk <<= 1) {
    float od = __shfl_xor(bd, msk, 64);
    int   oi = __shfl_xor(bi, msk, 64);
    float os = __shfl_xor(s, msk, 64);
    float m = fminf(bd, od);
    s = s * __expf(m - bd) + os * __expf(m - od);
    if (od < bd || (od == bd && oi < bi)) bi = oi;
    bd = m;
  }
  if (l == 0) { red[w * 4] = bd; red[w * 4 + 1] = s; red[w * 4 + 2] = (float)bi; }
  __syncthreads();
  if (t == 0) {
    float m = red[0], mi = red[2];
    #pragma unroll
    for (int c = 1; c < 4; ++c) {
      float od = red[c * 4], oi = red[c * 4 + 2];
      if (od < m || (od == m && oi < mi)) mi = oi;
      m = fminf(m, od);
    }
    float S = 0.f;
    #pragma unroll
    for (int c = 0; c < 4; ++c) S += red[c * 4 + 1] * __expf(m - red[c * 4]);
    red[14] = logf(S) - m;                 // LSE of (-dist)
    out[(size_t)ROWS * NF + row] = mi;     // preds
  }
  __syncthreads();
  const float L = red[14];

  // pass 2: logp = -d - L from LDS, nt store
  for (int c = t; c < 2500; c += 256) {
    f4v v = *reinterpret_cast<const f4v*>(&rowd[c * 4]);
    v = -v - L;
    __builtin_nontemporal_store(v, reinterpret_cast<f4v*>(po) + c);
  }
}

extern "C" void kernel_launch(void* const* d_in, const int* in_sizes, int n_in,
                              void* d_out, int out_size, void* d_ws, size_t ws_size,
                              hipStream_t stream) {
  const int*   roles   = (const int*)d_in[0];
  const float* hidden  = (const float*)d_in[1];
  const float* filler  = (const float*)d_in[2];
  const float* roleemb = (const float*)d_in[3];
  const float* W       = (const float*)d_in[4];
  const float* bias    = (const float*)d_in[5];
  float* out = (float*)d_out;

  float* ws = (float*)d_ws;
  float*          ht    = ws;                               // 4,194,304 f32
  unsigned short* fg2   = (unsigned short*)(ws + 4194304);  // 8192 x 512 bf16 (hi|lo)
  unsigned short* fl2   = (unsigned short*)(ws + 6291456);  // 10240 x 512 bf16 (hi|lo)
  float*          fgn   = ws + 8912896;                     // 8192
  float*          fln   = fgn + 8192;                       // 10240 (pad=1e30)

  k_cvt_filler<<<2560, 256, 0, stream>>>(filler, fl2, fln);
  k_gemm1<<<512, 256, 0, stream>>>(hidden, W, bias, ht);
  k_fg2<<<256, 256, 0, stream>>>(roles, roleemb, ht, fg2, fgn);
  k_dist<<<512, 256, 0, stream>>>(fg2, fl2, fgn, fln, out);
  k_final<<<8192, 256, 0, stream>>>(out);
}

// Round 21
// 515.744 us; speedup vs baseline: 1.0279x; 1.0279x over previous
//
#include <hip/hip_runtime.h>
#include <hip/hip_bf16.h>
#include <float.h>
#include <math.h>

#define ROWS 8192     // B*S
#define NF   10000    // n_fillers
#define NPAD 10240    // 80 * 128

typedef short s8v __attribute__((ext_vector_type(8)));
typedef float f4v __attribute__((ext_vector_type(4)));

#define GLD16(g, l) __builtin_amdgcn_global_load_lds((const __attribute__((address_space(1))) void*)(g), (__attribute__((address_space(3))) void*)(l), 16, 0, 0)

__device__ inline unsigned short f2bf(float x) {
  __hip_bfloat16 h = __float2bfloat16(x);
  return __builtin_bit_cast(unsigned short, h);
}
__device__ inline float bf2f(unsigned short u) {
  __hip_bfloat16 h = __builtin_bit_cast(__hip_bfloat16, u);
  return __bfloat162float(h);
}

// ---------------- filler: row norms + hi/lo bf16 conversion (rows padded to NPAD) ----------------
__global__ __launch_bounds__(256) void k_cvt_filler(const float* __restrict__ filler,
                                                    unsigned short* __restrict__ fl2,
                                                    float* __restrict__ fln) {
  int row = blockIdx.x * 4 + (threadIdx.x >> 6);
  int lane = threadIdx.x & 63;
  if (row >= NPAD) return;
  if (row < NF) {
    float4 v = reinterpret_cast<const float4*>(filler + (size_t)row * 256)[lane];
    float s = v.x * v.x + v.y * v.y + v.z * v.z + v.w * v.w;
    #pragma unroll
    for (int off = 32; off >= 1; off >>= 1) s += __shfl_xor(s, off, 64);
    if (lane == 0) fln[row] = s;
    float xs[4] = {v.x, v.y, v.z, v.w};
    unsigned short h[4], lo[4];
    #pragma unroll
    for (int j = 0; j < 4; ++j) { h[j] = f2bf(xs[j]); lo[j] = f2bf(xs[j] - bf2f(h[j])); }
    uint2 hh = make_uint2(h[0] | ((unsigned)h[1] << 16), h[2] | ((unsigned)h[3] << 16));
    uint2 ll = make_uint2(lo[0] | ((unsigned)lo[1] << 16), lo[2] | ((unsigned)lo[3] << 16));
    *reinterpret_cast<uint2*>(fl2 + (size_t)row * 512 + lane * 4) = hh;
    *reinterpret_cast<uint2*>(fl2 + (size_t)row * 512 + 256 + lane * 4) = ll;
  } else {
    *reinterpret_cast<uint2*>(fl2 + (size_t)row * 512 + lane * 4) = make_uint2(0, 0);
    *reinterpret_cast<uint2*>(fl2 + (size_t)row * 512 + 256 + lane * 4) = make_uint2(0, 0);
    if (lane == 0) fln[row] = 1e30f;
  }
}

// ---------------- GEMM1: ht[b, r*256+f] = sum_k hidden[b,k]*W[f*256+r,k] + bias[f*256+r]
__global__ __launch_bounds__(256) void k_gemm1(const float* __restrict__ hidden,
                                               const float* __restrict__ W,
                                               const float* __restrict__ bias,
                                               float* __restrict__ ht) {
  __shared__ float As[64][68];
  __shared__ float Bs[64][136];
  __shared__ float biasS[128];
  const int tid = threadIdx.x;
  const int nbase = blockIdx.x * 128;
  const int r = nbase >> 8;
  const int f0 = nbase & 255;
  const int tm = tid >> 4, tn = tid & 15;
  const int m0 = tm * 4, n0 = tn * 8;

  if (tid < 128) biasS[tid] = bias[(size_t)(f0 + tid) * 256 + r];

  float acc[4][8];
  #pragma unroll
  for (int i = 0; i < 4; ++i)
    #pragma unroll
    for (int j = 0; j < 8; ++j) acc[i][j] = 0.f;

  for (int kt = 0; kt < 16; ++kt) {
    __syncthreads();
    #pragma unroll
    for (int i = 0; i < 4; ++i) {
      int q = tid + i * 256;
      int b = q >> 4, kq = q & 15;
      float4 v = *reinterpret_cast<const float4*>(hidden + (size_t)b * 1024 + kt * 64 + kq * 4);
      As[kq * 4 + 0][b] = v.x;
      As[kq * 4 + 1][b] = v.y;
      As[kq * 4 + 2][b] = v.z;
      As[kq * 4 + 3][b] = v.w;
    }
    #pragma unroll
    for (int i = 0; i < 8; ++i) {
      int q = tid + i * 256;
      int nl = q >> 4, kq = q & 15;
      size_t wrow = (size_t)(f0 + nl) * 256 + r;
      float4 v = *reinterpret_cast<const float4*>(W + wrow * 1024 + kt * 64 + kq * 4);
      Bs[kq * 4 + 0][nl] = v.x;
      Bs[kq * 4 + 1][nl] = v.y;
      Bs[kq * 4 + 2][nl] = v.z;
      Bs[kq * 4 + 3][nl] = v.w;
    }
    __syncthreads();
    #pragma unroll
    for (int kk = 0; kk < 64; ++kk) {
      float4 a  = *reinterpret_cast<const float4*>(&As[kk][m0]);
      float4 b0 = *reinterpret_cast<const float4*>(&Bs[kk][n0]);
      float4 b1 = *reinterpret_cast<const float4*>(&Bs[kk][n0 + 4]);
      float av[4] = {a.x, a.y, a.z, a.w};
      float bv[8] = {b0.x, b0.y, b0.z, b0.w, b1.x, b1.y, b1.z, b1.w};
      #pragma unroll
      for (int i = 0; i < 4; ++i)
        #pragma unroll
        for (int j = 0; j < 8; ++j) acc[i][j] += av[i] * bv[j];
    }
  }
  #pragma unroll
  for (int i = 0; i < 4; ++i) {
    int b = m0 + i;
    float4 o0 = make_float4(acc[i][0] + biasS[n0 + 0], acc[i][1] + biasS[n0 + 1],
                            acc[i][2] + biasS[n0 + 2], acc[i][3] + biasS[n0 + 3]);
    float4 o1 = make_float4(acc[i][4] + biasS[n0 + 4], acc[i][5] + biasS[n0 + 5],
                            acc[i][6] + biasS[n0 + 6], acc[i][7] + biasS[n0 + 7]);
    float* p = ht + (size_t)b * 65536 + nbase + n0;
    *reinterpret_cast<float4*>(p)     = o0;
    *reinterpret_cast<float4*>(p + 4) = o1;
  }
}

// ---------------- fg (fused): compute fg, emit hi/lo bf16 (K-concat) + row norms ----------------
__global__ __launch_bounds__(256) void k_fg2(const int* __restrict__ roles,
                                             const float* __restrict__ role_emb,
                                             const float* __restrict__ ht,
                                             unsigned short* __restrict__ fg2,
                                             float* __restrict__ fgn) {
  __shared__ float As[64][40];
  __shared__ float Bs[64][264];
  __shared__ int sidx[32];
  const int tid = threadIdx.x;
  const int b = blockIdx.x >> 2;
  const int sbase = (blockIdx.x & 3) * 32;
  const int tm = tid >> 5, tn = tid & 31;
  const int m0 = tm * 4, n0 = tn * 8;
  if (tid < 32) sidx[tid] = roles[b * 128 + sbase + tid];

  float acc[4][8];
  #pragma unroll
  for (int i = 0; i < 4; ++i)
    #pragma unroll
    for (int j = 0; j < 8; ++j) acc[i][j] = 0.f;

  for (int kt = 0; kt < 4; ++kt) {
    __syncthreads();
    #pragma unroll
    for (int i = 0; i < 2; ++i) {
      int q = tid + i * 256;
      int s = q >> 4, rq = q & 15;
      float4 v = *reinterpret_cast<const float4*>(role_emb + (size_t)sidx[s] * 256 + kt * 64 + rq * 4);
      As[rq * 4 + 0][s] = v.x;
      As[rq * 4 + 1][s] = v.y;
      As[rq * 4 + 2][s] = v.z;
      As[rq * 4 + 3][s] = v.w;
    }
    #pragma unroll
    for (int i = 0; i < 16; ++i) {
      int q = tid + i * 256;
      int rr = q >> 6, fq = q & 63;
      float4 v = *reinterpret_cast<const float4*>(ht + (size_t)b * 65536 + (size_t)(kt * 64 + rr) * 256 + fq * 4);
      *reinterpret_cast<float4*>(&Bs[rr][fq * 4]) = v;
    }
    __syncthreads();
    #pragma unroll
    for (int kk = 0; kk < 64; ++kk) {
      float4 a  = *reinterpret_cast<const float4*>(&As[kk][m0]);
      float4 b0 = *reinterpret_cast<const float4*>(&Bs[kk][n0]);
      float4 b1 = *reinterpret_cast<const float4*>(&Bs[kk][n0 + 4]);
      float av[4] = {a.x, a.y, a.z, a.w};
      float bv[8] = {b0.x, b0.y, b0.z, b0.w, b1.x, b1.y, b1.z, b1.w};
      #pragma unroll
      for (int i = 0; i < 4; ++i)
        #pragma unroll
        for (int j = 0; j < 8; ++j) acc[i][j] += av[i] * bv[j];
    }
  }
  #pragma unroll
  for (int i = 0; i < 4; ++i) {
    const int grow = b * 128 + sbase + m0 + i;
    float nrm = 0.f;
    unsigned int hp[4], lp[4];
    #pragma unroll
    for (int j = 0; j < 8; j += 2) {
      float x0 = acc[i][j], x1 = acc[i][j + 1];
      nrm += x0 * x0 + x1 * x1;
      unsigned short h0 = f2bf(x0), h1 = f2bf(x1);
      unsigned short l0 = f2bf(x0 - bf2f(h0)), l1 = f2bf(x1 - bf2f(h1));
      hp[j >> 1] = h0 | ((unsigned)h1 << 16);
      lp[j >> 1] = l0 | ((unsigned)l1 << 16);
    }
    *reinterpret_cast<uint4*>(fg2 + (size_t)grow * 512 + n0)       = make_uint4(hp[0], hp[1], hp[2], hp[3]);
    *reinterpret_cast<uint4*>(fg2 + (size_t)grow * 512 + 256 + n0) = make_uint4(lp[0], lp[1], lp[2], lp[3]);
    #pragma unroll
    for (int msk = 1; msk <= 16; msk <<= 1) nrm += __shfl_xor(nrm, msk, 64);
    if (tn == 0) fgn[grow] = nrm;
  }
}

// ---------------- MFMA distance GEMM: R15/R19 verbatim (proven 247us) ----------------
// 128x128 tile, 8 waves (2Mx4N, 64x32 each), BK=64 dbuf, 10-strip n-loop, 2 blocks/CU,
// nt f4 dist stores via LDS bounce. mt confined to 8 panels/XCD -> A L2-resident.
__global__ __launch_bounds__(512, 4) void k_dist(const unsigned short* __restrict__ fg2,
                                                 const unsigned short* __restrict__ fl2,
                                                 const float* __restrict__ fgn,
                                                 const float* __restrict__ fln,
                                                 float* __restrict__ out) {
  __shared__ __align__(16) char lds[2][32768];    // per buf: A 16KB | B 16KB
  __shared__ float rn2s[128];
  const int tid = threadIdx.x;
  const int w = tid >> 6, l = tid & 63;
  const int g = l >> 4, lr = l & 15;
  const int mt  = (blockIdx.x & 7) * 8 + ((blockIdx.x >> 3) & 7);   // XCD gets 8 A-panels
  const int grp = blockIdx.x >> 6;                                  // 0..7
  const int rbase = mt << 7;
  const int wm = (w >> 2) << 6;   // 0 / 64
  const int wn = (w & 3) << 5;    // 0,32,64,96

  if (tid < 128) rn2s[tid] = fgn[rbase + tid];

  // staging chunk geometry: 1024 x 16B chunks per 128x64 tile; pre-swizzled global source
  int rowC[2], swC[2];
  #pragma unroll
  for (int t = 0; t < 2; ++t) {
    int p = tid + t * 512;
    int row = p >> 3, c = p & 7;
    rowC[t] = row;
    swC[t] = (c ^ (row & 7)) << 3;
  }
  // ds_read offsets: row stride 128B, chunk XOR (row&7) -> conflict-free (proven R3/R9/R11)
  int offA[4], offB[2];
  #pragma unroll
  for (int i = 0; i < 4; ++i) { int r = wm + i * 16 + lr; offA[i] = r * 128 + ((g ^ (r & 7)) << 4); }
  #pragma unroll
  for (int j = 0; j < 2; ++j) { int r = wn + j * 16 + lr; offB[j] = 16384 + r * 128 + ((g ^ (r & 7)) << 4); }

  // hi/lo K mapping: kt 0-3 hiA*hiB, 4-7 loA*hiB, 8-11 hiA*loB
  auto kAof = [](int kt) { return ((kt & 3) << 6) + ((kt >= 4 && kt < 8) ? 256 : 0); };
  auto kBof = [](int kt) { return ((kt & 3) << 6) + ((kt >= 8) ? 256 : 0); };

  auto stage = [&](int buf, int kt, int nb) {
    const int kA = kAof(kt), kB = kBof(kt);
    char* bA = &lds[buf][0]     + w * 1024;
    char* bB = &lds[buf][16384] + w * 1024;
    #pragma unroll
    for (int t = 0; t < 2; ++t) {
      GLD16(fg2 + ((size_t)(rbase + rowC[t]) * 512 + kA + swC[t]), bA + t * 8192);
      GLD16(fl2 + ((size_t)(nb    + rowC[t]) * 512 + kB + swC[t]), bB + t * 8192);
    }
  };

  stage(0, 0, grp << 7);   // prologue for strip 0
  __syncthreads();

  for (int s = 0; s < 10; ++s) {
    const int nt = grp + s * 8;
    const int nbase = nt << 7;
    float cnr[2];
    #pragma unroll
    for (int j = 0; j < 2; ++j) cnr[j] = fln[nbase + wn + j * 16 + lr];

    f4v acc[4][2];
    #pragma unroll
    for (int i = 0; i < 4; ++i)
      #pragma unroll
      for (int j = 0; j < 2; ++j) acc[i][j] = (f4v)0.f;

    for (int kt = 0; kt < 12; ++kt) {
      if (kt < 11)      stage((kt + 1) & 1, kt + 1, nbase);
      else if (s < 9)   stage(0, 0, (nt + 8) << 7);   // cross-strip prefetch into buf0
      const char* A = lds[kt & 1];
      #pragma unroll
      for (int s2 = 0; s2 < 2; ++s2) {
        s8v va[4], vb[2];
        #pragma unroll
        for (int i = 0; i < 4; ++i) va[i] = *reinterpret_cast<const s8v*>(A + (offA[i] ^ (s2 << 6)));
        #pragma unroll
        for (int j = 0; j < 2; ++j) vb[j] = *reinterpret_cast<const s8v*>(A + (offB[j] ^ (s2 << 6)));
        #pragma unroll
        for (int i = 0; i < 4; ++i)
          #pragma unroll
          for (int j = 0; j < 2; ++j)
            acc[i][j] = __builtin_amdgcn_mfma_f32_16x16x32_bf16(va[i], vb[j], acc[i][j], 0, 0, 0);
      }
      __syncthreads();
    }

    // ---- lean epilogue: d=sqrt(...), LDS bounce in buf1 (buf0 holds next strip's kt0) ----
    float* scr = reinterpret_cast<float*>(&lds[1][0]);   // 32 rows x 132 f32
    const int rem = NF - nbase;
    const int c4lim = (rem >= 128) ? 32 : (rem > 0 ? (rem >> 2) : 0);
    const int lbase = (wm >> 6) << 4;                    // 0 or 16

    #pragma unroll
    for (int i = 0; i < 4; ++i) {
      #pragma unroll
      for (int j = 0; j < 2; ++j) {
        const int cloc = wn + (j << 4) + lr;
        #pragma unroll
        for (int r = 0; r < 4; ++r) {
          const int lrow = lbase + (g << 2) + r;
          const float r2 = rn2s[wm + (i << 4) + (g << 2) + r];
          float d = sqrtf(fmaxf(r2 - 2.0f * acc[i][j][r] + cnr[j], 0.f));
          scr[lrow * 132 + cloc] = d;
        }
      }
      __syncthreads();
      #pragma unroll
      for (int t2 = 0; t2 < 2; ++t2) {
        const int id2 = tid + (t2 << 9);
        const int rr2 = id2 >> 5, c4 = id2 & 31;
        f4v v = *reinterpret_cast<const f4v*>(scr + rr2 * 132 + (c4 << 2));
        if (c4 < c4lim) {
          const int grow = rbase + ((rr2 < 16) ? ((i << 4) + rr2) : (64 + (i << 4) + rr2 - 16));
          __builtin_nontemporal_store(v, reinterpret_cast<f4v*>(out + (size_t)grow * NF + nbase + (c4 << 2)));
        }
      }
      __syncthreads();
    }
  }
}

// ---------------- per-row: LDS-staged, ONLINE softmax in pass 1, then logp = -d - LSE ----------
__global__ __launch_bounds__(256) void k_final(float* __restrict__ out) {
  const int row = blockIdx.x;
  __shared__ __align__(16) float rowd[10000];
  __shared__ float red[16];
  const int t = threadIdx.x;
  const int w = t >> 6, l = t & 63;
  float* po = out + (size_t)row * NF;

  // pass 1: nt-load -> LDS stage + per-thread ONLINE (min, argmin, sum exp(m - d))
  float bd = FLT_MAX; int bi = 0; float s = 0.f;
  for (int c = t; c < 2500; c += 256) {
    f4v v = __builtin_nontemporal_load(reinterpret_cast<const f4v*>(po) + c);
    *reinterpret_cast<f4v*>(&rowd[c * 4]) = v;
    const int base = c * 4;
    #pragma unroll
    for (int q = 0; q < 4; ++q) {
      float d = v[q];
      if (d < bd) {            // new min: rescale, then this elem contributes exp(0)=1
        s = s * __expf(d - bd) + 1.f;
        bd = d; bi = base + q;
      } else {
        s += __expf(bd - d);
      }
    }
  }
  // wave reduce: LSE-merge (m,s) + argmin with index tie-break
  #pragma unroll
  for (int msk = 1; msk <= 32; msk <<= 1) {
    float od = __shfl_xor(bd, msk, 64);
    int   oi = __shfl_xor(bi, msk, 64);
    float os = __shfl_xor(s, msk, 64);
    float m = fminf(bd, od);
    s = s * __expf(m - bd) + os * __expf(m - od);
    if (od < bd || (od == bd && oi < bi)) bi = oi;
    bd = m;
  }
  if (l == 0) { red[w * 4] = bd; red[w * 4 + 1] = s; red[w * 4 + 2] = (float)bi; }
  __syncthreads();
  if (t == 0) {
    float m = red[0], mi = red[2];
    #pragma unroll
    for (int c = 1; c < 4; ++c) {
      float od = red[c * 4], oi = red[c * 4 + 2];
      if (od < m || (od == m && oi < mi)) mi = oi;
      m = fminf(m, od);
    }
    float S = 0.f;
    #pragma unroll
    for (int c = 0; c < 4; ++c) S += red[c * 4 + 1] * __expf(m - red[c * 4]);
    red[14] = logf(S) - m;                 // LSE of (-dist)
    out[(size_t)ROWS * NF + row] = mi;     // preds
  }
  __syncthreads();
  const float L = red[14];

  // pass 2: logp = -d - L from LDS, nt store
  for (int c = t; c < 2500; c += 256) {
    f4v v = *reinterpret_cast<const f4v*>(&rowd[c * 4]);
    v = -v - L;
    __builtin_nontemporal_store(v, reinterpret_cast<f4v*>(po) + c);
  }
}

extern "C" void kernel_launch(void* const* d_in, const int* in_sizes, int n_in,
                              void* d_out, int out_size, void* d_ws, size_t ws_size,
                              hipStream_t stream) {
  const int*   roles   = (const int*)d_in[0];
  const float* hidden  = (const float*)d_in[1];
  const float* filler  = (const float*)d_in[2];
  const float* roleemb = (const float*)d_in[3];
  const float* W       = (const float*)d_in[4];
  const float* bias    = (const float*)d_in[5];
  float* out = (float*)d_out;

  float* ws = (float*)d_ws;
  float*          ht    = ws;                               // 4,194,304 f32
  unsigned short* fg2   = (unsigned short*)(ws + 4194304);  // 8192 x 512 bf16 (hi|lo)
  unsigned short* fl2   = (unsigned short*)(ws + 6291456);  // 10240 x 512 bf16 (hi|lo)
  float*          fgn   = ws + 8912896;                     // 8192
  float*          fln   = fgn + 8192;                       // 10240 (pad=1e30)

  k_cvt_filler<<<2560, 256, 0, stream>>>(filler, fl2, fln);
  k_gemm1<<<512, 256, 0, stream>>>(hidden, W, bias, ht);
  k_fg2<<<256, 256, 0, stream>>>(roles, roleemb, ht, fg2, fgn);
  k_dist<<<512, 512, 0, stream>>>(fg2, fl2, fgn, fln, out);
  k_final<<<8192, 256, 0, stream>>>(out);
}